// Round 15
// baseline (153.771 us; speedup 1.0000x reference)
//
#include <hip/hip_runtime.h>
#include <hip/hip_bf16.h>

#define STATE 16
#define DNA_C 4
#define HID   128
#define FAN1  52
#define HH    256
#define WW    256
#define HW    (HH * WW)

typedef unsigned short u16;
typedef unsigned int   u32;
typedef short bf8 __attribute__((ext_vector_type(8)));
typedef float f32x4 __attribute__((ext_vector_type(4)));

__device__ __forceinline__ u32 pk(float a, float b) {
    __hip_bfloat162 t = __float22bfloat162_rn(make_float2(a, b));  // v_cvt_pk_bf16_f32
    union { __hip_bfloat162 h; u32 u; } c; c.h = t; return c.u;
}
__device__ __forceinline__ u16 f2bf(float f) {
    union { __hip_bfloat16 h; u16 u; } c; c.h = __float2bfloat16(f); return c.u;
}

// w1 [128][52] f32 -> bf16 [128][64], DOUBLY permuted (identical to round 13):
//  * k-permutation: knew = 16w + t (t0-3 x, t4-7 gx, t8-11 gy, t12-15 dna(w==0)/pad)
//  * M-permutation: physical row p=16m+4g+r holds true hidden H = 32(m>>1)+8g+4(m&1)+r
//    -> L1 D-fragment IS the L2 B-fragment (register-only layer-2 exchange).
// w2 [16][128] -> bf16 plain.
__global__ void prep_weights(const float* __restrict__ w1, const float* __restrict__ w2,
                             u16* __restrict__ wb) {
    int i = blockIdx.x * 256 + threadIdx.x;   // 0..10239
    if (i < 128 * 64) {
        int p = i >> 6, knew = i & 63;
        int m = p >> 4, g = (p >> 2) & 3, r = p & 3;
        int hrow = 32 * (m >> 1) + 8 * g + 4 * (m & 1) + r;   // true hidden row at physical p
        int w = knew >> 4, t = knew & 15;
        float v = 0.f;
        if (t < 4)        v = w1[hrow * FAN1 + 4 * w + t];
        else if (t < 8)   v = w1[hrow * FAN1 + 16 + 4 * w + (t - 4)];
        else if (t < 12)  v = w1[hrow * FAN1 + 32 + 4 * w + (t - 8)];
        else if (w == 0)  v = w1[hrow * FAN1 + 48 + (t - 12)];
        wb[i] = f2bf(v);
    } else if (i < 128 * 64 + 16 * 128) {
        wb[i] = f2bf(w2[i - 128 * 64]);
    }
}

__global__ __launch_bounds__(256, 4) void update_net15(
    const float* __restrict__ x,    // [B,16,256,256]
    const float* __restrict__ dna,  // [B,4,256,256]
    const u16*   __restrict__ wb,   // permuted bf16 w1 [128][64], w2 [16][128]
    float* __restrict__ out)        // [B,16,256,256]
{
    // feat: [256 px][64 k] bf16, 128B rows, 16B chunks swizzled chunk ^= (px>>2)&7. 32 KB.
    // Feature phase cross-wave -> one barrier. feat_lds write-once/read-only (r13).
    // w1 A-fragments are NOT register-resident: re-loaded per m-half from global wb
    // (20 KB, L1/L2-hot). An opaque zero offset per g4 stops LICM from hoisting the
    // loads back into long-lived registers. This drops peak register demand below the
    // 4-waves/SIMD cap (128) and keeps all accumulators in arch VGPRs (no accvgpr moves).
    __shared__ __align__(16) u16 feat_lds[256 * 64];

    const int tid  = threadIdx.x;
    const int lane = tid & 63;
    const int wv   = tid >> 6;
    const int row  = blockIdx.x;
    const int b    = row >> 8;
    const int y    = row & 255;
    const bool ht  = (y > 0), hb = (y < HH - 1);   // block-uniform

    // ---- feature phase: wave wv -> channels 4wv..4wv+3, full row, 4 px/lane ----
    {
        const int px0 = lane * 4;
        const float* base = x + (((size_t)(b * STATE + 4 * wv)) * HH + y) * WW + px0;

        f32x4 xm[4], gx[4], gy[4];
        #pragma unroll
        for (int c = 0; c < 4; ++c) {
            const float* p = base + (size_t)c * HW;
            f32x4 m4 = *(const f32x4*)p;
            f32x4 t4 = {0.f,0.f,0.f,0.f}, b4 = {0.f,0.f,0.f,0.f};
            if (ht) t4 = *(const f32x4*)(p - WW);
            if (hb) b4 = *(const f32x4*)(p + WW);
            f32x4 cs, d;
            #pragma unroll
            for (int i = 0; i < 4; ++i) {
                cs[i] = fmaf(2.f, m4[i], t4[i] + b4[i]);   // colsum t+2m+b
                d[i]  = b4[i] - t4[i];
            }
            float csL = __shfl_up(cs[3], 1);
            float csR = __shfl_down(cs[0], 1);
            float dL  = __shfl_up(d[3], 1);
            float dR  = __shfl_down(d[0], 1);
            if (lane == 0)  { csL = 0.f; dL = 0.f; }       // image left border (zero pad)
            if (lane == 63) { csR = 0.f; dR = 0.f; }       // image right border
            xm[c] = m4;
            gx[c][0] = cs[1] - csL;   gx[c][1] = cs[2] - cs[0];
            gx[c][2] = cs[3] - cs[1]; gx[c][3] = csR - cs[2];
            gy[c][0] = fmaf(2.f, d[0], dL + d[1]);
            gy[c][1] = fmaf(2.f, d[1], d[0] + d[2]);
            gy[c][2] = fmaf(2.f, d[2], d[1] + d[3]);
            gy[c][3] = fmaf(2.f, d[3], d[2] + dR);
        }
        f32x4 dn[4] = {{0,0,0,0},{0,0,0,0},{0,0,0,0},{0,0,0,0}};
        if (wv == 0) {
            #pragma unroll
            for (int dc = 0; dc < 4; ++dc)
                dn[dc] = *(const f32x4*)(dna + (((size_t)(b * DNA_C + dc)) * HH + y) * WW + px0);
        }
        const int s = lane & 7;   // (px>>2)&7 for all 4 px of this lane
        #pragma unroll
        for (int i = 0; i < 4; ++i) {
            u16* rowp = &feat_lds[(px0 + i) * 64];
            uint4 c0 = make_uint4(pk(xm[0][i], xm[1][i]), pk(xm[2][i], xm[3][i]),
                                  pk(gx[0][i], gx[1][i]), pk(gx[2][i], gx[3][i]));
            uint4 c1 = make_uint4(pk(gy[0][i], gy[1][i]), pk(gy[2][i], gy[3][i]),
                                  pk(dn[0][i], dn[1][i]), pk(dn[2][i], dn[3][i]));
            *(uint4*)&rowp[8 * ((2 * wv)     ^ s)] = c0;   // knew 16wv..+7  : x | gx
            *(uint4*)&rowp[8 * ((2 * wv + 1) ^ s)] = c1;   // knew 16wv+8..15: gy | dna/pad
        }
    }

    const int fj = lane & 15;   // A-row / B-col / D-col
    const int fg = lane >> 4;   // k-group (A/B), row-group (D)
    const int f4 = fj >> 2;     // feat read swizzle base: sg(g4) = (4*g4 + f4) & 7

    const u16* w1b = wb;             // [128][64] doubly permuted
    const u16* w2b = wb + 128 * 64;  // [16][128]

    // a2 stays register-resident (16 regs, reused every g4)
    bf8 a2[4];
    #pragma unroll
    for (int kt = 0; kt < 4; ++kt)
        a2[kt] = *(const bf8*)&w2b[fj * 128 + 32 * kt + 8 * fg];

    __syncthreads();   // feature phase is cross-wave

    #pragma unroll
    for (int g4 = 0; g4 < 4; ++g4) {
        // opaque zero: the w1 fragment loads below cannot be proven loop-invariant,
        // so LICM cannot hoist them out of the g4 loop into 64 long-lived registers.
        int og4 = 0;
        asm volatile("" : "+v"(og4));
        const u16* w1p = w1b + og4;

        const int r  = wv * 64 + g4 * 16 + fj;
        const int sg = (4 * g4 + f4) & 7;
        bf8 b0 = *(const bf8*)&feat_lds[r * 64 + 8 * ((0 + fg) ^ sg)];
        bf8 b1 = *(const bf8*)&feat_lds[r * 64 + 8 * ((4 + fg) ^ sg)];

        // ---- layer 1 in two m-halves; w1 fragments streamed from L1-hot global ----
        u32 w[8][2];
        #pragma unroll
        for (int mh = 0; mh < 2; ++mh) {
            bf8 af[4][2];
            #pragma unroll
            for (int mm = 0; mm < 4; ++mm) {
                const int m = mh * 4 + mm;
                af[mm][0] = *(const bf8*)&w1p[(16 * m + fj) * 64 + 8 * fg];
                af[mm][1] = *(const bf8*)&w1p[(16 * m + fj) * 64 + 32 + 8 * fg];
            }
            f32x4 hc[4];
            #pragma unroll
            for (int mm = 0; mm < 4; ++mm) {
                f32x4 z = {0.f, 0.f, 0.f, 0.f};
                z = __builtin_amdgcn_mfma_f32_16x16x32_bf16(af[mm][0], b0, z, 0, 0, 0);
                hc[mm] = __builtin_amdgcn_mfma_f32_16x16x32_bf16(af[mm][1], b1, z, 0, 0, 0);
            }
            #pragma unroll
            for (int mm = 0; mm < 4; ++mm) {
                const int m = mh * 4 + mm;
                w[m][0] = pk(fmaxf(hc[mm][0], 0.f), fmaxf(hc[mm][1], 0.f));
                w[m][1] = pk(fmaxf(hc[mm][2], 0.f), fmaxf(hc[mm][3], 0.f));
            }
        }

        // ---- layer 2: B-fragment from the lane's OWN words (register-only, r13) ----
        f32x4 uacc = {0.f, 0.f, 0.f, 0.f};
        #pragma unroll
        for (int kt = 0; kt < 4; ++kt) {
            union { u32 u[4]; bf8 v; } bb;
            bb.u[0] = w[2 * kt][0];
            bb.u[1] = w[2 * kt][1];
            bb.u[2] = w[2 * kt + 1][0];
            bb.u[3] = w[2 * kt + 1][1];
            uacc = __builtin_amdgcn_mfma_f32_16x16x32_bf16(a2[kt], bb.v, uacc, 0, 0, 0);
        }

        const int xo = wv * 64 + g4 * 16 + fj;
        float* po = out + (((size_t)(b * STATE + 4 * fg)) * HH + y) * WW + xo;
        #pragma unroll
        for (int rr = 0; rr < 4; ++rr)
            po[(size_t)rr * HW] = uacc[rr];
    }
}

extern "C" void kernel_launch(void* const* d_in, const int* in_sizes, int n_in,
                              void* d_out, int out_size, void* d_ws, size_t ws_size,
                              hipStream_t stream) {
    const float* x   = (const float*)d_in[0];
    const float* dna = (const float*)d_in[1];
    const float* w1  = (const float*)d_in[2];
    const float* w2  = (const float*)d_in[3];
    float* out = (float*)d_out;
    u16* wb = (u16*)d_ws;   // 10240 u16 = 20 KB

    prep_weights<<<dim3(40), dim3(256), 0, stream>>>(w1, w2, wb);

    const int B = in_sizes[0] / (STATE * HH * WW);   // 16
    update_net15<<<dim3(B * HH), dim3(256), 0, stream>>>(x, dna, wb, out);
}

// Round 16
// 68.770 us; speedup vs baseline: 2.2360x; 2.2360x over previous
//
#include <hip/hip_runtime.h>
#include <hip/hip_bf16.h>

#define STATE 16
#define DNA_C 4
#define HID   128
#define FAN1  52
#define HH    256
#define WW    256
#define HW    (HH * WW)

typedef unsigned short u16;
typedef unsigned int   u32;
typedef short bf8 __attribute__((ext_vector_type(8)));
typedef float f32x4 __attribute__((ext_vector_type(4)));

__device__ __forceinline__ u32 pk(float a, float b) {
    __hip_bfloat162 t = __float22bfloat162_rn(make_float2(a, b));  // v_cvt_pk_bf16_f32
    union { __hip_bfloat162 h; u32 u; } c; c.h = t; return c.u;
}
__device__ __forceinline__ u16 f2bf(float f) {
    union { __hip_bfloat16 h; u16 u; } c; c.h = __float2bfloat16(f); return c.u;
}

// w1 [128][52] f32 -> bf16 [128][64], DOUBLY permuted (identical to round 13):
//  * k-permutation: knew = 16w + t (t0-3 x, t4-7 gx, t8-11 gy, t12-15 dna(w==0)/pad)
//  * M-permutation: physical row p=16m+4g+r holds true hidden H = 32(m>>1)+8g+4(m&1)+r
//    -> L1 D-fragment IS the L2 B-fragment (register-only layer-2 exchange).
// w2 [16][128] -> bf16 plain.
__global__ void prep_weights(const float* __restrict__ w1, const float* __restrict__ w2,
                             u16* __restrict__ wb) {
    int i = blockIdx.x * 256 + threadIdx.x;   // 0..10239
    if (i < 128 * 64) {
        int p = i >> 6, knew = i & 63;
        int m = p >> 4, g = (p >> 2) & 3, r = p & 3;
        int hrow = 32 * (m >> 1) + 8 * g + 4 * (m & 1) + r;   // true hidden row at physical p
        int w = knew >> 4, t = knew & 15;
        float v = 0.f;
        if (t < 4)        v = w1[hrow * FAN1 + 4 * w + t];
        else if (t < 8)   v = w1[hrow * FAN1 + 16 + 4 * w + (t - 4)];
        else if (t < 12)  v = w1[hrow * FAN1 + 32 + 4 * w + (t - 8)];
        else if (w == 0)  v = w1[hrow * FAN1 + 48 + (t - 12)];
        wb[i] = f2bf(v);
    } else if (i < 128 * 64 + 16 * 128) {
        wb[i] = f2bf(w2[i - 128 * 64]);
    }
}

__global__ __launch_bounds__(256, 3) void update_net16(
    const float* __restrict__ x,    // [B,16,256,256]
    const float* __restrict__ dna,  // [B,4,256,256]
    const u16*   __restrict__ wb,   // permuted bf16 w1 [128][64], w2 [16][128]
    float* __restrict__ out,        // [B,16,256,256]
    int nrows)                      // B*256
{
    // Persistent chunked-row version of round 13 (body unchanged):
    //  * 768 blocks (3/CU), block i owns a CONTIGUOUS chunk of rows -> weight prologue
    //    amortized, no drain tail, and 2/3 of the x-halo rows are L1/L2-hot on each
    //    iteration (row y+1 re-reads rows y,y+1 loaded by iteration y).
    //  * feat: [256 px][64 k] bf16, chunks swizzled chunk ^= (px>>2)&7, 32 KB.
    //  * Two barriers per row: feature writes are cross-wave; next row's writes must
    //    wait for this row's MFMA reads.
    __shared__ __align__(16) u16 feat_lds[256 * 64];

    const int tid  = threadIdx.x;
    const int lane = tid & 63;
    const int wv   = tid >> 6;
    const int fj   = lane & 15;   // A-row / B-col / D-col
    const int fg   = lane >> 4;   // k-group (A/B), row-group (D)
    const int f4   = fj >> 2;     // feat read swizzle base

    // ---- weight fragments ONCE per block (register-resident a1/a2, r13 layout) ----
    const u16* w1b = wb;             // [128][64] doubly permuted
    const u16* w2b = wb + 128 * 64;  // [16][128]
    bf8 a1[8][2];
    #pragma unroll
    for (int m = 0; m < 8; ++m) {
        #pragma unroll
        for (int kt = 0; kt < 2; ++kt)
            a1[m][kt] = *(const bf8*)&w1b[(16 * m + fj) * 64 + 32 * kt + 8 * fg];
    }
    bf8 a2[4];
    #pragma unroll
    for (int kt = 0; kt < 4; ++kt)
        a2[kt] = *(const bf8*)&w2b[fj * 128 + 32 * kt + 8 * fg];

    // ---- bijective contiguous chunking of rows over blocks ----
    const int ngrid = gridDim.x;
    const int q = nrows / ngrid, rr = nrows - q * ngrid;
    const int bid = blockIdx.x;
    const int start = (bid < rr) ? bid * (q + 1) : rr * (q + 1) + (bid - rr) * q;
    const int cnt   = (bid < rr) ? q + 1 : q;

    for (int it = 0; it < cnt; ++it) {
        const int yr = start + it;
        const int b  = yr >> 8;
        const int y  = yr & 255;
        const bool ht = (y > 0), hb = (y < HH - 1);   // block-uniform

        // ---- feature phase: wave wv -> channels 4wv..4wv+3, full row, 4 px/lane ----
        {
            const int px0 = lane * 4;
            const float* base = x + (((size_t)(b * STATE + 4 * wv)) * HH + y) * WW + px0;

            f32x4 xm[4], gx[4], gy[4];
            #pragma unroll
            for (int c = 0; c < 4; ++c) {
                const float* p = base + (size_t)c * HW;
                f32x4 m4 = *(const f32x4*)p;
                f32x4 t4 = {0.f,0.f,0.f,0.f}, b4 = {0.f,0.f,0.f,0.f};
                if (ht) t4 = *(const f32x4*)(p - WW);
                if (hb) b4 = *(const f32x4*)(p + WW);
                f32x4 cs, d;
                #pragma unroll
                for (int i = 0; i < 4; ++i) {
                    cs[i] = fmaf(2.f, m4[i], t4[i] + b4[i]);   // colsum t+2m+b
                    d[i]  = b4[i] - t4[i];
                }
                float csL = __shfl_up(cs[3], 1);
                float csR = __shfl_down(cs[0], 1);
                float dL  = __shfl_up(d[3], 1);
                float dR  = __shfl_down(d[0], 1);
                if (lane == 0)  { csL = 0.f; dL = 0.f; }       // image left border
                if (lane == 63) { csR = 0.f; dR = 0.f; }       // image right border
                xm[c] = m4;
                gx[c][0] = cs[1] - csL;   gx[c][1] = cs[2] - cs[0];
                gx[c][2] = cs[3] - cs[1]; gx[c][3] = csR - cs[2];
                gy[c][0] = fmaf(2.f, d[0], dL + d[1]);
                gy[c][1] = fmaf(2.f, d[1], d[0] + d[2]);
                gy[c][2] = fmaf(2.f, d[2], d[1] + d[3]);
                gy[c][3] = fmaf(2.f, d[3], d[2] + dR);
            }
            f32x4 dn[4] = {{0,0,0,0},{0,0,0,0},{0,0,0,0},{0,0,0,0}};
            if (wv == 0) {
                #pragma unroll
                for (int dc = 0; dc < 4; ++dc)
                    dn[dc] = *(const f32x4*)(dna + (((size_t)(b * DNA_C + dc)) * HH + y) * WW + px0);
            }
            const int s = lane & 7;   // (px>>2)&7 for all 4 px of this lane
            #pragma unroll
            for (int i = 0; i < 4; ++i) {
                u16* rowp = &feat_lds[(px0 + i) * 64];
                uint4 c0 = make_uint4(pk(xm[0][i], xm[1][i]), pk(xm[2][i], xm[3][i]),
                                      pk(gx[0][i], gx[1][i]), pk(gx[2][i], gx[3][i]));
                uint4 c1 = make_uint4(pk(gy[0][i], gy[1][i]), pk(gy[2][i], gy[3][i]),
                                      pk(dn[0][i], dn[1][i]), pk(dn[2][i], dn[3][i]));
                *(uint4*)&rowp[8 * ((2 * wv)     ^ s)] = c0;   // knew 16wv..+7  : x | gx
                *(uint4*)&rowp[8 * ((2 * wv + 1) ^ s)] = c1;   // knew 16wv+8..15: gy | dna/pad
            }
        }

        __syncthreads();   // feature phase is cross-wave

        #pragma unroll
        for (int g4 = 0; g4 < 4; ++g4) {
            const int r  = wv * 64 + g4 * 16 + fj;
            const int sg = (4 * g4 + f4) & 7;
            bf8 b0 = *(const bf8*)&feat_lds[r * 64 + 8 * ((0 + fg) ^ sg)];
            bf8 b1 = *(const bf8*)&feat_lds[r * 64 + 8 * ((4 + fg) ^ sg)];

            // ---- layer 1 in two m-halves; relu+pack into lane-local words ----
            u32 w[8][2];
            #pragma unroll
            for (int mh = 0; mh < 2; ++mh) {
                f32x4 hc[4];
                #pragma unroll
                for (int mm = 0; mm < 4; ++mm) {
                    const int m = mh * 4 + mm;
                    f32x4 z = {0.f, 0.f, 0.f, 0.f};
                    z = __builtin_amdgcn_mfma_f32_16x16x32_bf16(a1[m][0], b0, z, 0, 0, 0);
                    hc[mm] = __builtin_amdgcn_mfma_f32_16x16x32_bf16(a1[m][1], b1, z, 0, 0, 0);
                }
                #pragma unroll
                for (int mm = 0; mm < 4; ++mm) {
                    const int m = mh * 4 + mm;
                    w[m][0] = pk(fmaxf(hc[mm][0], 0.f), fmaxf(hc[mm][1], 0.f));
                    w[m][1] = pk(fmaxf(hc[mm][2], 0.f), fmaxf(hc[mm][3], 0.f));
                }
            }

            // ---- layer 2: B-fragment from the lane's OWN words (register-only, r13) ----
            f32x4 uacc = {0.f, 0.f, 0.f, 0.f};
            #pragma unroll
            for (int kt = 0; kt < 4; ++kt) {
                union { u32 u[4]; bf8 v; } bb;
                bb.u[0] = w[2 * kt][0];
                bb.u[1] = w[2 * kt][1];
                bb.u[2] = w[2 * kt + 1][0];
                bb.u[3] = w[2 * kt + 1][1];
                uacc = __builtin_amdgcn_mfma_f32_16x16x32_bf16(a2[kt], bb.v, uacc, 0, 0, 0);
            }

            const int xo = wv * 64 + g4 * 16 + fj;
            float* po = out + (((size_t)(b * STATE + 4 * fg)) * HH + y) * WW + xo;
            #pragma unroll
            for (int rr2 = 0; rr2 < 4; ++rr2)
                po[(size_t)rr2 * HW] = uacc[rr2];
        }

        __syncthreads();   // this row's MFMA reads done before next row's feat writes
    }
}

extern "C" void kernel_launch(void* const* d_in, const int* in_sizes, int n_in,
                              void* d_out, int out_size, void* d_ws, size_t ws_size,
                              hipStream_t stream) {
    const float* x   = (const float*)d_in[0];
    const float* dna = (const float*)d_in[1];
    const float* w1  = (const float*)d_in[2];
    const float* w2  = (const float*)d_in[3];
    float* out = (float*)d_out;
    u16* wb = (u16*)d_ws;   // 10240 u16 = 20 KB

    prep_weights<<<dim3(40), dim3(256), 0, stream>>>(w1, w2, wb);

    const int B = in_sizes[0] / (STATE * HH * WW);   // 16
    const int nrows = B * HH;                        // 4096
    const int grid = (nrows < 768) ? nrows : 768;    // 3 blocks/CU persistent
    update_net16<<<dim3(grid), dim3(256), 0, stream>>>(x, dna, wb, out, nrows);
}